// Round 1
// baseline (311.188 us; speedup 1.0000x reference)
//
#include <hip/hip_runtime.h>
#include <hip/hip_bf16.h>
#include <math.h>

#define N_NODES 40000
#define N_EDGES 640000
#define D 128
#define LN_EPS 1e-5f

__device__ __forceinline__ float f4get(const float4& v, int j) {
    return j == 0 ? v.x : j == 1 ? v.y : j == 2 ? v.z : v.w;
}

// ---------------------------------------------------------------------------
// GEMM: h_mean = x@Wm + bm ; h_var = exp(x@Wv + bv)
// block 256 threads, BM=64 nodes, BN=128 (full), K staged in chunks of 16
// ---------------------------------------------------------------------------
__global__ __launch_bounds__(256) void gemm_kernel(
    const float* __restrict__ x, const float* __restrict__ Wm,
    const float* __restrict__ bm, const float* __restrict__ Wv,
    const float* __restrict__ bv, float* __restrict__ h_mean,
    float* __restrict__ h_var)
{
    __shared__ float xs[64][24];     // 16 k-cols, padded to 24 (16B-aligned rows)
    __shared__ float wms[16][128];
    __shared__ float wvs[16][128];

    const int t = threadIdx.x;
    const int nbase = blockIdx.x * 64;
    const int tx = t & 31;   // col group: cols tx*4 .. tx*4+3
    const int ty = t >> 5;   // row group: rows ty*8 .. ty*8+7

    float accm[8][4] = {};
    float accv[8][4] = {};

    for (int k0 = 0; k0 < D; k0 += 16) {
        if (k0) __syncthreads();
        // stage x tile 64x16 (one float4 per thread)
        {
            int row = t >> 2, c4 = (t & 3) << 2;
            float4 v = *(const float4*)&x[(size_t)(nbase + row) * D + k0 + c4];
            xs[row][c4 + 0] = v.x; xs[row][c4 + 1] = v.y;
            xs[row][c4 + 2] = v.z; xs[row][c4 + 3] = v.w;
        }
        // stage W tiles 16x128 each (two float4 per thread per matrix)
        #pragma unroll
        for (int j = 0; j < 2; ++j) {
            int f4 = t + 256 * j;
            int row = f4 >> 5, c4 = (f4 & 31) << 2;
            *(float4*)&wms[row][c4] = *(const float4*)&Wm[(size_t)(k0 + row) * D + c4];
            *(float4*)&wvs[row][c4] = *(const float4*)&Wv[(size_t)(k0 + row) * D + c4];
        }
        __syncthreads();

        #pragma unroll
        for (int kk4 = 0; kk4 < 4; ++kk4) {
            float4 xr[8];
            #pragma unroll
            for (int r = 0; r < 8; ++r)
                xr[r] = *(float4*)&xs[ty * 8 + r][kk4 * 4];
            #pragma unroll
            for (int j = 0; j < 4; ++j) {
                float4 wm4 = *(float4*)&wms[kk4 * 4 + j][tx * 4];
                float4 wv4 = *(float4*)&wvs[kk4 * 4 + j][tx * 4];
                #pragma unroll
                for (int r = 0; r < 8; ++r) {
                    float xv = f4get(xr[r], j);
                    accm[r][0] = fmaf(xv, wm4.x, accm[r][0]);
                    accm[r][1] = fmaf(xv, wm4.y, accm[r][1]);
                    accm[r][2] = fmaf(xv, wm4.z, accm[r][2]);
                    accm[r][3] = fmaf(xv, wm4.w, accm[r][3]);
                    accv[r][0] = fmaf(xv, wv4.x, accv[r][0]);
                    accv[r][1] = fmaf(xv, wv4.y, accv[r][1]);
                    accv[r][2] = fmaf(xv, wv4.z, accv[r][2]);
                    accv[r][3] = fmaf(xv, wv4.w, accv[r][3]);
                }
            }
        }
    }

    float4 bm4 = *(const float4*)&bm[tx * 4];
    float4 bv4 = *(const float4*)&bv[tx * 4];
    #pragma unroll
    for (int r = 0; r < 8; ++r) {
        size_t node = nbase + ty * 8 + r;
        float4 om = make_float4(accm[r][0] + bm4.x, accm[r][1] + bm4.y,
                                accm[r][2] + bm4.z, accm[r][3] + bm4.w);
        *(float4*)&h_mean[node * D + tx * 4] = om;
        float4 ov = make_float4(expf(accv[r][0] + bv4.x), expf(accv[r][1] + bv4.y),
                                expf(accv[r][2] + bv4.z), expf(accv[r][3] + bv4.w));
        *(float4*)&h_var[node * D + tx * 4] = ov;
    }
}

// ---------------------------------------------------------------------------
// Histogram of destination (row) indices
// ---------------------------------------------------------------------------
__global__ void hist_kernel(const int* __restrict__ row, int* __restrict__ counts)
{
    int e = blockIdx.x * blockDim.x + threadIdx.x;
    if (e < N_EDGES) atomicAdd(&counts[row[e]], 1);
}

// ---------------------------------------------------------------------------
// Single-block exclusive scan over 40000 counts -> rowstart[40001], cursor copy
// ---------------------------------------------------------------------------
__global__ __launch_bounds__(1024) void scan_kernel(
    const int* __restrict__ counts, int* __restrict__ rowstart,
    int* __restrict__ cursor)
{
    __shared__ int tmp[1024];
    const int t = threadIdx.x;
    const int CH = 40;                 // 1024*40 = 40960 >= 40000
    const int base = t * CH;

    int s = 0;
    for (int i = 0; i < CH; ++i) {
        int idx = base + i;
        if (idx < N_NODES) s += counts[idx];
    }
    tmp[t] = s;
    __syncthreads();
    // Hillis-Steele inclusive scan
    for (int off = 1; off < 1024; off <<= 1) {
        int v = tmp[t];
        int add = (t >= off) ? tmp[t - off] : 0;
        __syncthreads();
        tmp[t] = v + add;
        __syncthreads();
    }
    int run = (t > 0) ? tmp[t - 1] : 0;  // exclusive prefix
    for (int i = 0; i < CH; ++i) {
        int idx = base + i;
        if (idx < N_NODES) {
            rowstart[idx] = run;
            cursor[idx] = run;
            run += counts[idx];
        }
    }
    if (t == 1023) rowstart[N_NODES] = tmp[1023];
}

// ---------------------------------------------------------------------------
// Scatter edges into CSR order: {col, ewm, ewv} reordered by destination row
// ---------------------------------------------------------------------------
__global__ void scatter_kernel(
    const int* __restrict__ row, const int* __restrict__ col,
    const float* __restrict__ ewm, const float* __restrict__ ewv,
    int* __restrict__ cursor, int* __restrict__ ecol,
    float* __restrict__ eewm, float* __restrict__ eewv)
{
    int e = blockIdx.x * blockDim.x + threadIdx.x;
    if (e >= N_EDGES) return;
    int r = row[e];
    int pos = atomicAdd(&cursor[r], 1);
    ecol[pos] = col[e];
    eewm[pos] = ewm[e];
    eewv[pos] = ewv[e];
}

// ---------------------------------------------------------------------------
// Per-node aggregation + degree normalization + LayerNorm, fused.
// One 128-thread block per node; thread d owns feature d.
// ---------------------------------------------------------------------------
__global__ __launch_bounds__(128) void agg_kernel(
    const float* __restrict__ h_mean, const float* __restrict__ h_var,
    const int* __restrict__ rowstart, const int* __restrict__ ecol,
    const float* __restrict__ eewm, const float* __restrict__ eewv,
    const float* __restrict__ gamma, const float* __restrict__ beta,
    float* __restrict__ out)
{
    const int n = blockIdx.x;
    const int d = threadIdx.x;
    const int start = rowstart[n];
    const int end = rowstart[n + 1];

    float am = 0.f, av = 0.f;
    for (int e = start; e < end; ++e) {
        int c = ecol[e];
        float wm = eewm[e], wv = eewv[e];
        float hm = h_mean[(size_t)c * D + d];
        float hv = h_var[(size_t)c * D + d];
        am = fmaf(hm, wm, am);
        av += wm * wm * hv + hm * hm * wv;
    }
    float degi = 1.0f / fmaxf((float)(end - start), 1.0f);
    am *= degi;
    av *= degi * degi;

    // LayerNorm over 128 features (2 waves)
    __shared__ float red[2];
    const int lane = d & 63, wid = d >> 6;

    float s = am;
    #pragma unroll
    for (int off = 32; off >= 1; off >>= 1) s += __shfl_xor(s, off);
    if (lane == 0) red[wid] = s;
    __syncthreads();
    float mu = (red[0] + red[1]) * (1.0f / 128.0f);
    float diff = am - mu;
    __syncthreads();

    float q = diff * diff;
    #pragma unroll
    for (int off = 32; off >= 1; off >>= 1) q += __shfl_xor(q, off);
    if (lane == 0) red[wid] = q;
    __syncthreads();
    float var = (red[0] + red[1]) * (1.0f / 128.0f);

    float o = diff * rsqrtf(var + LN_EPS) * gamma[d] + beta[d];
    out[(size_t)n * D + d] = o;                          // out_mean (LN'd)
    out[(size_t)N_NODES * D + (size_t)n * D + d] = av;   // out_var
}

// ---------------------------------------------------------------------------
extern "C" void kernel_launch(void* const* d_in, const int* in_sizes, int n_in,
                              void* d_out, int out_size, void* d_ws, size_t ws_size,
                              hipStream_t stream)
{
    const float* x     = (const float*)d_in[0];
    const int*   eidx  = (const int*)d_in[1];
    const float* ewm   = (const float*)d_in[2];
    const float* ewv   = (const float*)d_in[3];
    const float* Wm    = (const float*)d_in[4];
    const float* bm    = (const float*)d_in[5];
    const float* Wv    = (const float*)d_in[6];
    const float* bv    = (const float*)d_in[7];
    const float* gamma = (const float*)d_in[8];
    const float* beta  = (const float*)d_in[9];
    const int* row = eidx;              // edge_index[0]
    const int* col = eidx + N_EDGES;    // edge_index[1]

    char* ws = (char*)d_ws;
    size_t off = 0;
    auto alloc = [&](size_t bytes) {
        void* p = ws + off;
        off += (bytes + 255) & ~(size_t)255;
        return p;
    };
    float* h_mean  = (float*)alloc((size_t)N_NODES * D * 4);
    float* h_var   = (float*)alloc((size_t)N_NODES * D * 4);
    int*   counts  = (int*)alloc((size_t)N_NODES * 4);
    int*   rowstart= (int*)alloc((size_t)(N_NODES + 1) * 4);
    int*   cursor  = (int*)alloc((size_t)N_NODES * 4);
    int*   ecol    = (int*)alloc((size_t)N_EDGES * 4);
    float* eewm    = (float*)alloc((size_t)N_EDGES * 4);
    float* eewv    = (float*)alloc((size_t)N_EDGES * 4);

    hipMemsetAsync(counts, 0, (size_t)N_NODES * 4, stream);

    gemm_kernel<<<N_NODES / 64, 256, 0, stream>>>(x, Wm, bm, Wv, bv, h_mean, h_var);
    hist_kernel<<<(N_EDGES + 255) / 256, 256, 0, stream>>>(row, counts);
    scan_kernel<<<1, 1024, 0, stream>>>(counts, rowstart, cursor);
    scatter_kernel<<<(N_EDGES + 255) / 256, 256, 0, stream>>>(
        row, col, ewm, ewv, cursor, ecol, eewm, eewv);
    agg_kernel<<<N_NODES, 128, 0, stream>>>(
        h_mean, h_var, rowstart, ecol, eewm, eewv, gamma, beta, (float*)d_out);
}

// Round 2
// 217.321 us; speedup vs baseline: 1.4319x; 1.4319x over previous
//
#include <hip/hip_runtime.h>
#include <hip/hip_bf16.h>
#include <math.h>

#define N_NODES 40000
#define N_EDGES 640000
#define D 128
#define LN_EPS 1e-5f
#define SCAN_B 512
#define SCAN_NB ((N_NODES + SCAN_B - 1) / SCAN_B)   // 79

__device__ __forceinline__ float f4get(const float4& v, int j) {
    return j == 0 ? v.x : j == 1 ? v.y : j == 2 ? v.z : v.w;
}

// ---------------------------------------------------------------------------
// GEMM: h_mean = x@Wm + bm ; h_var = exp(x@Wv + bv)
// block 256 threads, BM=64 nodes, BN=128 (full), K staged in chunks of 16
// ---------------------------------------------------------------------------
__global__ __launch_bounds__(256) void gemm_kernel(
    const float* __restrict__ x, const float* __restrict__ Wm,
    const float* __restrict__ bm, const float* __restrict__ Wv,
    const float* __restrict__ bv, float* __restrict__ h_mean,
    float* __restrict__ h_var)
{
    __shared__ float xs[64][24];
    __shared__ float wms[16][128];
    __shared__ float wvs[16][128];

    const int t = threadIdx.x;
    const int nbase = blockIdx.x * 64;
    const int tx = t & 31;
    const int ty = t >> 5;

    float accm[8][4] = {};
    float accv[8][4] = {};

    for (int k0 = 0; k0 < D; k0 += 16) {
        if (k0) __syncthreads();
        {
            int row = t >> 2, c4 = (t & 3) << 2;
            float4 v = *(const float4*)&x[(size_t)(nbase + row) * D + k0 + c4];
            xs[row][c4 + 0] = v.x; xs[row][c4 + 1] = v.y;
            xs[row][c4 + 2] = v.z; xs[row][c4 + 3] = v.w;
        }
        #pragma unroll
        for (int j = 0; j < 2; ++j) {
            int f4 = t + 256 * j;
            int row = f4 >> 5, c4 = (f4 & 31) << 2;
            *(float4*)&wms[row][c4] = *(const float4*)&Wm[(size_t)(k0 + row) * D + c4];
            *(float4*)&wvs[row][c4] = *(const float4*)&Wv[(size_t)(k0 + row) * D + c4];
        }
        __syncthreads();

        #pragma unroll
        for (int kk4 = 0; kk4 < 4; ++kk4) {
            float4 xr[8];
            #pragma unroll
            for (int r = 0; r < 8; ++r)
                xr[r] = *(float4*)&xs[ty * 8 + r][kk4 * 4];
            #pragma unroll
            for (int j = 0; j < 4; ++j) {
                float4 wm4 = *(float4*)&wms[kk4 * 4 + j][tx * 4];
                float4 wv4 = *(float4*)&wvs[kk4 * 4 + j][tx * 4];
                #pragma unroll
                for (int r = 0; r < 8; ++r) {
                    float xv = f4get(xr[r], j);
                    accm[r][0] = fmaf(xv, wm4.x, accm[r][0]);
                    accm[r][1] = fmaf(xv, wm4.y, accm[r][1]);
                    accm[r][2] = fmaf(xv, wm4.z, accm[r][2]);
                    accm[r][3] = fmaf(xv, wm4.w, accm[r][3]);
                    accv[r][0] = fmaf(xv, wv4.x, accv[r][0]);
                    accv[r][1] = fmaf(xv, wv4.y, accv[r][1]);
                    accv[r][2] = fmaf(xv, wv4.z, accv[r][2]);
                    accv[r][3] = fmaf(xv, wv4.w, accv[r][3]);
                }
            }
        }
    }

    float4 bm4 = *(const float4*)&bm[tx * 4];
    float4 bv4 = *(const float4*)&bv[tx * 4];
    #pragma unroll
    for (int r = 0; r < 8; ++r) {
        size_t node = nbase + ty * 8 + r;
        float4 om = make_float4(accm[r][0] + bm4.x, accm[r][1] + bm4.y,
                                accm[r][2] + bm4.z, accm[r][3] + bm4.w);
        *(float4*)&h_mean[node * D + tx * 4] = om;
        float4 ov = make_float4(expf(accv[r][0] + bv4.x), expf(accv[r][1] + bv4.y),
                                expf(accv[r][2] + bv4.z), expf(accv[r][3] + bv4.w));
        *(float4*)&h_var[node * D + tx * 4] = ov;
    }
}

// ---------------------------------------------------------------------------
// Histogram of destination (row) indices
// ---------------------------------------------------------------------------
__global__ void hist_kernel(const int* __restrict__ row, int* __restrict__ counts)
{
    int e = blockIdx.x * blockDim.x + threadIdx.x;
    if (e < N_EDGES) atomicAdd(&counts[row[e]], 1);
}

// ---------------------------------------------------------------------------
// Hierarchical scan, stage 1: per-block sums of counts
// ---------------------------------------------------------------------------
__global__ __launch_bounds__(SCAN_B) void scan_partial_kernel(
    const int* __restrict__ counts, int* __restrict__ partials)
{
    int idx = blockIdx.x * SCAN_B + threadIdx.x;
    int c = (idx < N_NODES) ? counts[idx] : 0;
    int lane = threadIdx.x & 63, wid = threadIdx.x >> 6;
    #pragma unroll
    for (int off = 32; off >= 1; off >>= 1) c += __shfl_xor(c, off);
    __shared__ int ws[SCAN_B / 64];
    if (lane == 0) ws[wid] = c;
    __syncthreads();
    if (threadIdx.x == 0) {
        int s = 0;
        #pragma unroll
        for (int i = 0; i < SCAN_B / 64; ++i) s += ws[i];
        partials[blockIdx.x] = s;
    }
}

// ---------------------------------------------------------------------------
// Hierarchical scan, stage 2: exclusive scan of the 79 block partials
// ---------------------------------------------------------------------------
__global__ __launch_bounds__(128) void scan_top_kernel(
    const int* __restrict__ partials, int* __restrict__ blockoff)
{
    __shared__ int tmp[128];
    int t = threadIdx.x;
    tmp[t] = (t < SCAN_NB) ? partials[t] : 0;
    __syncthreads();
    for (int off = 1; off < 128; off <<= 1) {
        int v = tmp[t];
        int a = (t >= off) ? tmp[t - off] : 0;
        __syncthreads();
        tmp[t] = v + a;
        __syncthreads();
    }
    if (t < SCAN_NB) blockoff[t] = (t > 0) ? tmp[t - 1] : 0;
}

// ---------------------------------------------------------------------------
// Hierarchical scan, stage 3: in-block exclusive scan + offset, write
// rowstart[] and cursor[]; last element writes rowstart[N_NODES]
// ---------------------------------------------------------------------------
__global__ __launch_bounds__(SCAN_B) void scan_write_kernel(
    const int* __restrict__ counts, const int* __restrict__ blockoff,
    int* __restrict__ rowstart, int* __restrict__ cursor)
{
    int idx = blockIdx.x * SCAN_B + threadIdx.x;
    int c = (idx < N_NODES) ? counts[idx] : 0;
    int lane = threadIdx.x & 63, wid = threadIdx.x >> 6;

    int inc = c;
    #pragma unroll
    for (int off = 1; off < 64; off <<= 1) {
        int u = __shfl_up(inc, off);
        if (lane >= off) inc += u;
    }
    __shared__ int ws[SCAN_B / 64];
    if (lane == 63) ws[wid] = inc;
    __syncthreads();
    if (threadIdx.x == 0) {
        int run = 0;
        #pragma unroll
        for (int i = 0; i < SCAN_B / 64; ++i) { int v = ws[i]; ws[i] = run; run += v; }
    }
    __syncthreads();
    int excl = inc - c + ws[wid] + blockoff[blockIdx.x];
    if (idx < N_NODES) {
        rowstart[idx] = excl;
        cursor[idx]   = excl;
        if (idx == N_NODES - 1) rowstart[N_NODES] = excl + c;
    }
}

// ---------------------------------------------------------------------------
// Scatter edges into CSR order: {col, ewm, ewv} reordered by destination row
// ---------------------------------------------------------------------------
__global__ void scatter_kernel(
    const int* __restrict__ row, const int* __restrict__ col,
    const float* __restrict__ ewm, const float* __restrict__ ewv,
    int* __restrict__ cursor, int* __restrict__ ecol,
    float* __restrict__ eewm, float* __restrict__ eewv)
{
    int e = blockIdx.x * blockDim.x + threadIdx.x;
    if (e >= N_EDGES) return;
    int r = row[e];
    int pos = atomicAdd(&cursor[r], 1);
    ecol[pos] = col[e];
    eewm[pos] = ewm[e];
    eewv[pos] = ewv[e];
}

// ---------------------------------------------------------------------------
// Per-node aggregation + degree normalization + LayerNorm, fused.
// ---------------------------------------------------------------------------
__global__ __launch_bounds__(128) void agg_kernel(
    const float* __restrict__ h_mean, const float* __restrict__ h_var,
    const int* __restrict__ rowstart, const int* __restrict__ ecol,
    const float* __restrict__ eewm, const float* __restrict__ eewv,
    const float* __restrict__ gamma, const float* __restrict__ beta,
    float* __restrict__ out)
{
    const int n = blockIdx.x;
    const int d = threadIdx.x;
    const int start = rowstart[n];
    const int end = rowstart[n + 1];

    float am = 0.f, av = 0.f;
    for (int e = start; e < end; ++e) {
        int c = ecol[e];
        float wm = eewm[e], wv = eewv[e];
        float hm = h_mean[(size_t)c * D + d];
        float hv = h_var[(size_t)c * D + d];
        am = fmaf(hm, wm, am);
        av += wm * wm * hv + hm * hm * wv;
    }
    float degi = 1.0f / fmaxf((float)(end - start), 1.0f);
    am *= degi;
    av *= degi * degi;

    __shared__ float red[2];
    const int lane = d & 63, wid = d >> 6;

    float s = am;
    #pragma unroll
    for (int off = 32; off >= 1; off >>= 1) s += __shfl_xor(s, off);
    if (lane == 0) red[wid] = s;
    __syncthreads();
    float mu = (red[0] + red[1]) * (1.0f / 128.0f);
    float diff = am - mu;
    __syncthreads();

    float q = diff * diff;
    #pragma unroll
    for (int off = 32; off >= 1; off >>= 1) q += __shfl_xor(q, off);
    if (lane == 0) red[wid] = q;
    __syncthreads();
    float var = (red[0] + red[1]) * (1.0f / 128.0f);

    float o = diff * rsqrtf(var + LN_EPS) * gamma[d] + beta[d];
    out[(size_t)n * D + d] = o;
    out[(size_t)N_NODES * D + (size_t)n * D + d] = av;
}

// ---------------------------------------------------------------------------
extern "C" void kernel_launch(void* const* d_in, const int* in_sizes, int n_in,
                              void* d_out, int out_size, void* d_ws, size_t ws_size,
                              hipStream_t stream)
{
    const float* x     = (const float*)d_in[0];
    const int*   eidx  = (const int*)d_in[1];
    const float* ewm   = (const float*)d_in[2];
    const float* ewv   = (const float*)d_in[3];
    const float* Wm    = (const float*)d_in[4];
    const float* bm    = (const float*)d_in[5];
    const float* Wv    = (const float*)d_in[6];
    const float* bv    = (const float*)d_in[7];
    const float* gamma = (const float*)d_in[8];
    const float* beta  = (const float*)d_in[9];
    const int* row = eidx;
    const int* col = eidx + N_EDGES;

    char* ws = (char*)d_ws;
    size_t off = 0;
    auto alloc = [&](size_t bytes) {
        void* p = ws + off;
        off += (bytes + 255) & ~(size_t)255;
        return p;
    };
    float* h_mean  = (float*)alloc((size_t)N_NODES * D * 4);
    float* h_var   = (float*)alloc((size_t)N_NODES * D * 4);
    int*   counts  = (int*)alloc((size_t)N_NODES * 4);
    int*   rowstart= (int*)alloc((size_t)(N_NODES + 1) * 4);
    int*   cursor  = (int*)alloc((size_t)N_NODES * 4);
    int*   ecol    = (int*)alloc((size_t)N_EDGES * 4);
    float* eewm    = (float*)alloc((size_t)N_EDGES * 4);
    float* eewv    = (float*)alloc((size_t)N_EDGES * 4);
    int*   partials= (int*)alloc((size_t)SCAN_NB * 4);
    int*   blockoff= (int*)alloc((size_t)SCAN_NB * 4);

    hipMemsetAsync(counts, 0, (size_t)N_NODES * 4, stream);

    gemm_kernel<<<N_NODES / 64, 256, 0, stream>>>(x, Wm, bm, Wv, bv, h_mean, h_var);
    hist_kernel<<<(N_EDGES + 255) / 256, 256, 0, stream>>>(row, counts);
    scan_partial_kernel<<<SCAN_NB, SCAN_B, 0, stream>>>(counts, partials);
    scan_top_kernel<<<1, 128, 0, stream>>>(partials, blockoff);
    scan_write_kernel<<<SCAN_NB, SCAN_B, 0, stream>>>(counts, blockoff, rowstart, cursor);
    scatter_kernel<<<(N_EDGES + 255) / 256, 256, 0, stream>>>(
        row, col, ewm, ewv, cursor, ecol, eewm, eewv);
    agg_kernel<<<N_NODES, 128, 0, stream>>>(
        h_mean, h_var, rowstart, ecol, eewm, eewv, gamma, beta, (float*)d_out);
}